// Round 7
// baseline (584.322 us; speedup 1.0000x reference)
//
#include <hip/hip_runtime.h>

typedef int int32x4 __attribute__((ext_vector_type(4)));

#define B_ 32
#define C_ 256
#define H_ 56
#define W_ 56
#define HP 58
#define WP 58

static constexpr float QSCALE = 255.0f / 8.0f;   // 31.875 (exact); x<1 -> n in [0,32]
static constexpr float D1 = 8.0f / 255.0f;

// ws layout: [Xq i8 padded NHWC][slack][Wt i8 swizzled][oscale f32[256]]
static constexpr size_t XQ_BYTES = (size_t)B_ * HP * WP * C_;     // 27,541,504
static constexpr size_t XQ_SPACE = XQ_BYTES + 32768;
static constexpr size_t WT_BYTES = 36ull * 16384;                 // 589,824
static constexpr size_t WS_NEED = XQ_SPACE + WT_BYTES + 2048;

__device__ __forceinline__ void gload_lds16(const void* g, void* l) {
  __builtin_amdgcn_global_load_lds((const __attribute__((address_space(1))) unsigned int*)g,
                                   (__attribute__((address_space(3))) unsigned int*)l,
                                   16, 0, 0);
}

// ---------------- Kernel 1: quantize input + NCHW -> padded NHWC i8 (+ border zeroing) -----
__global__ __launch_bounds__(256) void quant_transpose_i8(const float* __restrict__ x,
                                                          char* __restrict__ Xq) {
  __shared__ unsigned short T[W_ * 256];     // integer level n per [w][c]
  const int h = blockIdx.x;                  // 0..55 -> padded row h+1
  const int b = blockIdx.y;
  const int c = threadIdx.x;

  const float4* src = (const float4*)(x + (((size_t)b * C_ + c) * H_ + h) * W_);
#pragma unroll
  for (int i = 0; i < 14; ++i) {
    float4 v = src[i];
    float vals[4] = {v.x, v.y, v.z, v.w};
    const int w0 = i * 4;
#pragma unroll
    for (int j = 0; j < 4; ++j) {
      int n = (int)rintf(vals[j] * QSCALE);
      n = n < 0 ? 0 : (n > 255 ? 255 : n);   // x<1 keeps n<=32; clamp for safety
      T[(w0 + j) * 256 + c] = (unsigned short)n;
    }
  }
  __syncthreads();

  char* row = Xq + (((size_t)b * HP + (h + 1)) * WP) * 256;
  // side border columns 0 and 57 of this padded row
  if (threadIdx.x < 64) {
    *(unsigned int*)(row + threadIdx.x * 4) = 0u;
    *(unsigned int*)(row + (size_t)57 * 256 + threadIdx.x * 4) = 0u;
  }
  // top/bottom padded rows (h==0 -> row 0, h==55 -> row 57), fused (was zero_rows kernel)
  const int4 z4 = {0, 0, 0, 0};
  if (h == 0) {
    char* r0 = Xq + (((size_t)b * HP + 0) * WP) * 256;
    for (int i = threadIdx.x; i < WP * 16; i += 256) ((int4*)r0)[i] = z4;
  }
  if (h == 55) {
    char* r57 = Xq + (((size_t)b * HP + 57) * WP) * 256;
    for (int i = threadIdx.x; i < WP * 16; i += 256) ((int4*)r57)[i] = z4;
  }

  const int wid = threadIdx.x >> 6;
  const int lane = threadIdx.x & 63;
#pragma unroll
  for (int p = 0; p < 14; ++p) {
    const int w = p * 4 + wid;
    ushort4 v = *(const ushort4*)&T[w * 256 + lane * 4];
    unsigned int packed = (unsigned int)v.x | ((unsigned int)v.y << 8) |
                          ((unsigned int)v.z << 16) | ((unsigned int)v.w << 24);
    *(unsigned int*)(row + (size_t)(w + 1) * 256 + lane * 4) = packed;
  }
}

// ---------------- Kernel 2: fused absmax + i8 error-feedback quant, one block per c_out ----
// Wt layout: Wt[((cc*9+pos)*256 + co)*64 + ((j4 ^ ((co>>1)&3))*16) + e], ci = cc*64+j4*16+e.
__global__ __launch_bounds__(256) void prep_weights_i8(const float* __restrict__ w,
                                                       char* __restrict__ Wt,
                                                       float* __restrict__ oscale) {
  __shared__ __align__(16) float wf[2304];
  __shared__ __align__(16) char Wq[2304];       // [chunk=cc*9+p][ci&63]
  __shared__ float red[4];
  __shared__ float sbc;
  const int co = blockIdx.x;
  const int tid = threadIdx.x;

  const float4* src = (const float4*)(w + (size_t)co * 2304);
  float m = 0.f;
  for (int i = tid; i < 576; i += 256) {
    float4 v = src[i];
    *(float4*)&wf[i * 4] = v;
    m = fmaxf(fmaxf(fabsf(v.x), fabsf(v.y)), fmaxf(fmaxf(fabsf(v.z), fabsf(v.w)), m));
  }

#pragma unroll
  for (int off = 32; off; off >>= 1) m = fmaxf(m, __shfl_down(m, off));
  if ((tid & 63) == 0) red[tid >> 6] = m;
  __syncthreads();
  if (tid == 0) {
    m = fmaxf(fmaxf(red[0], red[1]), fmaxf(red[2], red[3]));
    m = fmaxf(m, 1e-20f);
    sbc = m;
    oscale[co] = (m / 127.f) * D1;
  }
  __syncthreads();

  if (tid < 9) {
    const int p = tid;
    const float s = sbc / 127.f;
    const float inv = 1.f / s;
    float carry = 0.f;
    for (int ci = 0; ci < 256; ++ci) {
      float t = wf[ci * 9 + p] + carry;
      float qf = rintf(t * inv);
      qf = fminf(fmaxf(qf, -128.f), 127.f);
      carry = t - qf * s;
      Wq[((ci >> 6) * 9 + p) * 64 + (ci & 63)] = (char)(int)qf;
    }
  }
  __syncthreads();

  if (tid < 144) {
    const int chunk = tid >> 2;        // cc*9 + p
    const int g = tid & 3;             // output 16B group
    const int fsw = (co >> 1) & 3;
    int4 v = *(const int4*)&Wq[chunk * 64 + ((g ^ fsw) << 4)];
    *(int4*)(Wt + ((size_t)(chunk * 256 + co)) * 64 + (g << 4)) = v;
  }
}

// ---------------- Kernel 3: implicit-GEMM conv, i8 MFMA 16x16x64 ---------------------------
// 512 threads = 8 waves: 2 row-pairs x 4 co-quarters. BM=256 co, BN=224 (4 output rows).
// 36 steps of K=64. W double-buffered (2x16KB), X double-buffered (2x21.75KB, 6 rows).
__global__ __launch_bounds__(512, 4) void conv_mfma_i8(const char* __restrict__ Xq,
                                                       const char* __restrict__ Wt,
                                                       const float* __restrict__ oscale,
                                                       float* __restrict__ out) {
  __shared__ __align__(16) char Wl[2][16384];
  __shared__ __align__(16) char Xl[2][348 * 64];     // 6 rows x 58 cols x 64 ci
  const int tid = threadIdx.x;
  const int wid = tid >> 6, lane = tid & 63;
  const int col = lane & 15, hi = lane >> 4;
  const int wpair = wid >> 2, wco = wid & 3;

  // XCD-aware bijective swizzle: 448 blocks = 8 XCDs x 56
  const int l = blockIdx.x;
  const int wk = (l & 7) * 56 + (l >> 3);
  const int by = wk % 14;
  const int b = wk / 14;
  const int h0 = 4 * by;            // first padded input row == first output row

  int nbase[7];
#pragma unroll
  for (int nf = 0; nf < 7; ++nf) {
    const int n_out = nf * 16 + col;
    const int r = n_out >= 56 ? 1 : 0;
    nbase[nf] = (2 * wpair + r) * WP + (n_out - r * 56);
  }

  int aoff[4];
#pragma unroll
  for (int mf = 0; mf < 4; ++mf) {
    const int co = wco * 64 + mf * 16 + col;
    aoff[mf] = co * 64 + ((hi ^ ((co >> 1) & 3)) << 4);
  }

  int32x4 acc[4][7];
#pragma unroll
  for (int mf = 0; mf < 4; ++mf)
#pragma unroll
    for (int nf = 0; nf < 7; ++nf) acc[mf][nf] = (int32x4){0, 0, 0, 0};

  const char* xrow = Xq + ((size_t)b * HP + h0) * WP * 256;

#define STAGE_W(src_, dst_)                                        \
  {                                                                \
    _Pragma("unroll") for (int p = 0; p < 2; ++p) {                \
      const int s = p * 512 + tid;                                 \
      gload_lds16((src_) + s * 16, (dst_) + s * 16);               \
    }                                                              \
  }
#define STAGE_X_PASS(c0_, dst_, p_)                                \
  {                                                                \
    const int s = (p_)*512 + tid;                                  \
    if (s < 1392) {                                                \
      const int nin = s >> 2;                                      \
      const int cdat = (s & 3) ^ ((nin >> 1) & 3);                 \
      gload_lds16(xrow + nin * 256 + (c0_) + cdat * 16, (dst_) + s * 16); \
    }                                                              \
  }

  STAGE_W(Wt, Wl[0]);
  STAGE_X_PASS(0, Xl[0], 0);
  STAGE_X_PASS(0, Xl[0], 1);
  STAGE_X_PASS(0, Xl[0], 2);
  __syncthreads();

#pragma unroll 1
  for (int cc = 0; cc < 4; ++cc) {
    char* wlA = Wl[cc & 1];             // current for even pos
    char* wlB = Wl[(cc & 1) ^ 1];       // current for odd pos
    const char* xl = Xl[cc & 1];
    char* xs = Xl[(cc & 1) ^ 1];
    const char* wchunk = Wt + (size_t)(cc * 9) * 16384;

#pragma unroll
    for (int pos = 0; pos < 9; ++pos) {
      // stage next W chunk into the other buffer
      if (!(cc == 3 && pos == 8)) STAGE_W(wchunk + (size_t)(pos + 1) * 16384,
                                          (pos & 1) ? wlA : wlB);
      // stage next X chunk, spread over pos 6/7/8
      if (cc < 3 && pos >= 6) STAGE_X_PASS((cc + 1) * 64, xs, pos - 6);

      const char* wl = (pos & 1) ? wlB : wlA;
      const int kh = pos / 3;
      const int poff = kh * WP + (pos - 3 * kh);

      int32x4 a0 = *(const int32x4*)(wl + aoff[0]);
      int32x4 a1 = *(const int32x4*)(wl + aoff[1]);
      int32x4 a2 = *(const int32x4*)(wl + aoff[2]);
      int32x4 a3 = *(const int32x4*)(wl + aoff[3]);
      __builtin_amdgcn_s_setprio(1);
#pragma unroll
      for (int nf = 0; nf < 7; ++nf) {
        const int nin = nbase[nf] + poff;
        int32x4 bb = *(const int32x4*)(xl + nin * 64 + ((hi ^ ((nin >> 1) & 3)) << 4));
        acc[0][nf] = __builtin_amdgcn_mfma_i32_16x16x64_i8(a0, bb, acc[0][nf], 0, 0, 0);
        acc[1][nf] = __builtin_amdgcn_mfma_i32_16x16x64_i8(a1, bb, acc[1][nf], 0, 0, 0);
        acc[2][nf] = __builtin_amdgcn_mfma_i32_16x16x64_i8(a2, bb, acc[2][nf], 0, 0, 0);
        acc[3][nf] = __builtin_amdgcn_mfma_i32_16x16x64_i8(a3, bb, acc[3][nf], 0, 0, 0);
      }
      __builtin_amdgcn_s_setprio(0);
      __syncthreads();
    }
  }
#undef STAGE_W
#undef STAGE_X_PASS

  // ---- epilogue: out = acc * oscale[co]; C row = co (hi*4 + r4), col = spatial ----
#pragma unroll
  for (int mf = 0; mf < 4; ++mf) {
    const int cbase = wco * 64 + mf * 16 + hi * 4;
    const float4 os = *(const float4*)(oscale + cbase);
#pragma unroll
    for (int nf = 0; nf < 7; ++nf) {
      const int n_out = nf * 16 + col;
      const int r = n_out >= 56 ? 1 : 0;
      const int hrow = h0 + 2 * wpair + r;
      const int wcol = n_out - r * 56;
      float* o = out + ((((size_t)b * 256 + cbase) * 56 + hrow) * 56 + wcol);
      o[0 * 3136] = (float)acc[mf][nf][0] * os.x;
      o[1 * 3136] = (float)acc[mf][nf][1] * os.y;
      o[2 * 3136] = (float)acc[mf][nf][2] * os.z;
      o[3 * 3136] = (float)acc[mf][nf][3] * os.w;
    }
  }
}

// ---------------- Fallback: naive direct conv (if ws too small) ----------------------------
__global__ void conv_naive(const float* __restrict__ x, const float* __restrict__ w,
                           float* __restrict__ out, int total) {
  int idx = blockIdx.x * 256 + threadIdx.x;
  if (idx >= total) return;
  const int wc = idx % 56;
  int t = idx / 56;
  const int hr = t % 56; t /= 56;
  const int co = t % 256;
  const int b = t / 256;
  float acc = 0.f;
  for (int ci = 0; ci < 256; ++ci) {
    const float* xb = x + (((size_t)b * 256 + ci) * 56) * 56;
    const float* wb = w + ((size_t)co * 256 + ci) * 9;
#pragma unroll
    for (int kh = 0; kh < 3; ++kh) {
      const int hh = hr + kh - 1;
      if (hh < 0 || hh >= 56) continue;
#pragma unroll
      for (int kw = 0; kw < 3; ++kw) {
        const int ww = wc + kw - 1;
        if (ww < 0 || ww >= 56) continue;
        const float q = rintf(xb[hh * 56 + ww] * QSCALE) * D1;
        acc += q * wb[kh * 3 + kw];
      }
    }
  }
  out[idx] = acc;
}

extern "C" void kernel_launch(void* const* d_in, const int* in_sizes, int n_in,
                              void* d_out, int out_size, void* d_ws, size_t ws_size,
                              hipStream_t stream) {
  (void)in_sizes; (void)n_in; (void)out_size;
  const float* x = (const float*)d_in[0];
  const float* w = (const float*)d_in[1];
  float* out = (float*)d_out;

  if (ws_size < WS_NEED) {
    const int total = B_ * C_ * H_ * W_;
    conv_naive<<<(total + 255) / 256, 256, 0, stream>>>(x, w, out, total);
    return;
  }

  char* Xq = (char*)d_ws;
  char* Wt = (char*)d_ws + XQ_SPACE;
  float* oscale = (float*)((char*)d_ws + XQ_SPACE + WT_BYTES);

  quant_transpose_i8<<<dim3(56, 32), 256, 0, stream>>>(x, Xq);
  prep_weights_i8<<<dim3(256), 256, 0, stream>>>(w, Wt, oscale);
  conv_mfma_i8<<<dim3(448), 512, 0, stream>>>(Xq, Wt, oscale, out);
}

// Round 8
// 124.659 us; speedup vs baseline: 4.6874x; 4.6874x over previous
//
#include <hip/hip_runtime.h>

typedef int int32x4 __attribute__((ext_vector_type(4)));

#define B_ 32
#define C_ 256
#define H_ 56
#define W_ 56
#define HP 58
#define WP 58

static constexpr float QSCALE = 255.0f / 8.0f;   // 31.875 (exact); x<1 -> n in [0,32]
static constexpr float D1 = 8.0f / 255.0f;

// ws layout: [Xq i8 padded NHWC][slack][Wt i8 swizzled][oscale f32[256]]
static constexpr size_t XQ_BYTES = (size_t)B_ * HP * WP * C_;     // 27,541,504
static constexpr size_t XQ_SPACE = XQ_BYTES + 32768;
static constexpr size_t WT_BYTES = 36ull * 16384;                 // 589,824
static constexpr size_t WS_NEED = XQ_SPACE + WT_BYTES + 2048;

__device__ __forceinline__ void gload_lds16(const void* g, void* l) {
  __builtin_amdgcn_global_load_lds((const __attribute__((address_space(1))) unsigned int*)g,
                                   (__attribute__((address_space(3))) unsigned int*)l,
                                   16, 0, 0);
}

// ---------------- Kernel 1: quantize input + NCHW -> padded NHWC i8 (+ border zeroing) -----
__global__ __launch_bounds__(256) void quant_transpose_i8(const float* __restrict__ x,
                                                          char* __restrict__ Xq) {
  __shared__ unsigned short T[W_ * 256];     // integer level n per [w][c]
  const int h = blockIdx.x;                  // 0..55 -> padded row h+1
  const int b = blockIdx.y;
  const int c = threadIdx.x;

  const float4* src = (const float4*)(x + (((size_t)b * C_ + c) * H_ + h) * W_);
#pragma unroll
  for (int i = 0; i < 14; ++i) {
    float4 v = src[i];
    float vals[4] = {v.x, v.y, v.z, v.w};
    const int w0 = i * 4;
#pragma unroll
    for (int j = 0; j < 4; ++j) {
      int n = (int)rintf(vals[j] * QSCALE);
      n = n < 0 ? 0 : (n > 255 ? 255 : n);   // x<1 keeps n<=32; clamp for safety
      T[(w0 + j) * 256 + c] = (unsigned short)n;
    }
  }
  __syncthreads();

  char* row = Xq + (((size_t)b * HP + (h + 1)) * WP) * 256;
  // side border columns 0 and 57 of this padded row
  if (threadIdx.x < 64) {
    *(unsigned int*)(row + threadIdx.x * 4) = 0u;
    *(unsigned int*)(row + (size_t)57 * 256 + threadIdx.x * 4) = 0u;
  }
  // top/bottom padded rows (h==0 -> row 0, h==55 -> row 57)
  const int4 z4 = {0, 0, 0, 0};
  if (h == 0) {
    char* r0 = Xq + (((size_t)b * HP + 0) * WP) * 256;
    for (int i = threadIdx.x; i < WP * 16; i += 256) ((int4*)r0)[i] = z4;
  }
  if (h == 55) {
    char* r57 = Xq + (((size_t)b * HP + 57) * WP) * 256;
    for (int i = threadIdx.x; i < WP * 16; i += 256) ((int4*)r57)[i] = z4;
  }

  const int wid = threadIdx.x >> 6;
  const int lane = threadIdx.x & 63;
#pragma unroll
  for (int p = 0; p < 14; ++p) {
    const int w = p * 4 + wid;
    ushort4 v = *(const ushort4*)&T[w * 256 + lane * 4];
    unsigned int packed = (unsigned int)v.x | ((unsigned int)v.y << 8) |
                          ((unsigned int)v.z << 16) | ((unsigned int)v.w << 24);
    *(unsigned int*)(row + (size_t)(w + 1) * 256 + lane * 4) = packed;
  }
}

// ---------------- Kernel 2: fused absmax + i8 error-feedback quant, one block per c_out ----
// Wt layout: Wt[((cc*9+pos)*256 + co)*64 + ((j4 ^ ((co>>1)&3))*16) + e], ci = cc*64+j4*16+e.
__global__ __launch_bounds__(256) void prep_weights_i8(const float* __restrict__ w,
                                                       char* __restrict__ Wt,
                                                       float* __restrict__ oscale) {
  __shared__ __align__(16) float wf[2304];
  __shared__ __align__(16) char Wq[2304];       // [chunk=cc*9+p][ci&63]
  __shared__ float red[4];
  __shared__ float sbc;
  const int co = blockIdx.x;
  const int tid = threadIdx.x;

  const float4* src = (const float4*)(w + (size_t)co * 2304);
  float m = 0.f;
  for (int i = tid; i < 576; i += 256) {
    float4 v = src[i];
    *(float4*)&wf[i * 4] = v;
    m = fmaxf(fmaxf(fabsf(v.x), fabsf(v.y)), fmaxf(fmaxf(fabsf(v.z), fabsf(v.w)), m));
  }

#pragma unroll
  for (int off = 32; off; off >>= 1) m = fmaxf(m, __shfl_down(m, off));
  if ((tid & 63) == 0) red[tid >> 6] = m;
  __syncthreads();
  if (tid == 0) {
    m = fmaxf(fmaxf(red[0], red[1]), fmaxf(red[2], red[3]));
    m = fmaxf(m, 1e-20f);
    sbc = m;
    oscale[co] = (m / 127.f) * D1;
  }
  __syncthreads();

  if (tid < 9) {
    const int p = tid;
    const float s = sbc / 127.f;
    const float inv = 1.f / s;
    float carry = 0.f;
    for (int ci = 0; ci < 256; ++ci) {
      float t = wf[ci * 9 + p] + carry;
      float qf = rintf(t * inv);
      qf = fminf(fmaxf(qf, -128.f), 127.f);
      carry = t - qf * s;
      Wq[((ci >> 6) * 9 + p) * 64 + (ci & 63)] = (char)(int)qf;
    }
  }
  __syncthreads();

  if (tid < 144) {
    const int chunk = tid >> 2;        // cc*9 + p
    const int g = tid & 3;             // output 16B group
    const int fsw = (co >> 1) & 3;
    int4 v = *(const int4*)&Wq[chunk * 64 + ((g ^ fsw) << 4)];
    *(int4*)(Wt + ((size_t)(chunk * 256 + co)) * 64 + (g << 4)) = v;
  }
}

// ---------------- staging helpers -----------------------------------------------------------
__device__ __forceinline__ void stage_w(const char* __restrict__ src, char* dst, int tid) {
#pragma unroll
  for (int p = 0; p < 4; ++p) {
    const int s = p * 256 + tid;           // 1024 x 16B, linear both sides (pre-swizzled mem)
    gload_lds16(src + s * 16, dst + s * 16);
  }
}

__device__ __forceinline__ void stage_x(const char* __restrict__ xrow, int c0, char* dst, int tid) {
#pragma unroll
  for (int p = 0; p < 4; ++p) {
    const int s = p * 256 + tid;           // 1024 slots; rows 232..255 load in-ws garbage
    const int nin = s >> 2;
    const int cdat = (s & 3) ^ ((nin >> 1) & 3);
    gload_lds16(xrow + nin * 256 + c0 + cdat * 16, dst + s * 16);
  }
}

// ---------------- Kernel 3: implicit-GEMM conv, i8 MFMA 16x16x64 ---------------------------
// 4 waves. BM=256 co (4 m-frags/wave), BN=112 (2 rows, 7 n-frags). 36 steps of K=64.
// W double-buffered (32 KB), X single-buffered (16 KB) -> 48 KB LDS -> 3 blocks/CU.
__global__ __launch_bounds__(256) void conv_mfma_i8(const char* __restrict__ Xq,
                                                    const char* __restrict__ Wt,
                                                    const float* __restrict__ oscale,
                                                    float* __restrict__ out) {
  __shared__ __align__(16) char Wl[2][16384];
  __shared__ __align__(16) char Xl[16384];
  const int tid = threadIdx.x;
  const int wid = tid >> 6, lane = tid & 63;
  const int col = lane & 15, hi = lane >> 4;

  // XCD-aware bijective swizzle: 896 blocks = 8 XCDs x 112
  const int l = blockIdx.x;
  const int wk = (l & 7) * 112 + (l >> 3);
  const int by = wk % 28;
  const int b = wk / 28;
  const int h0 = 2 * by;

  int nbase[7];
#pragma unroll
  for (int nf = 0; nf < 7; ++nf) {
    const int n_out = nf * 16 + col;
    const int r = n_out >= 56 ? 1 : 0;
    nbase[nf] = r * WP + (n_out - r * 56);
  }

  int aoff[4];
#pragma unroll
  for (int mf = 0; mf < 4; ++mf) {
    const int co = wid * 64 + mf * 16 + col;
    aoff[mf] = co * 64 + ((hi ^ ((co >> 1) & 3)) << 4);
  }

  int32x4 acc[4][7];
#pragma unroll
  for (int mf = 0; mf < 4; ++mf)
#pragma unroll
    for (int nf = 0; nf < 7; ++nf) acc[mf][nf] = (int32x4){0, 0, 0, 0};

  const char* xrow = Xq + ((size_t)b * HP + h0) * WP * 256;

  stage_w(Wt, Wl[0], tid);
  stage_x(xrow, 0, Xl, tid);
  __syncthreads();

  int cc = 0, pos = 0;
#pragma unroll 1
  for (int step = 0; step < 36; ++step) {
    if (step < 35) stage_w(Wt + (size_t)(step + 1) * 16384, Wl[(step + 1) & 1], tid);

    const char* wl = Wl[step & 1];
    const int kh = (pos * 11) >> 5;              // pos/3 for pos<9
    const int poff = kh * WP + (pos - 3 * kh);

    int32x4 a0 = *(const int32x4*)(wl + aoff[0]);
    int32x4 a1 = *(const int32x4*)(wl + aoff[1]);
    int32x4 a2 = *(const int32x4*)(wl + aoff[2]);
    int32x4 a3 = *(const int32x4*)(wl + aoff[3]);
    __builtin_amdgcn_s_setprio(1);
#pragma unroll
    for (int nf = 0; nf < 7; ++nf) {
      const int nin = nbase[nf] + poff;
      int32x4 bb = *(const int32x4*)(Xl + nin * 64 + ((hi ^ ((nin >> 1) & 3)) << 4));
      acc[0][nf] = __builtin_amdgcn_mfma_i32_16x16x64_i8(a0, bb, acc[0][nf], 0, 0, 0);
      acc[1][nf] = __builtin_amdgcn_mfma_i32_16x16x64_i8(a1, bb, acc[1][nf], 0, 0, 0);
      acc[2][nf] = __builtin_amdgcn_mfma_i32_16x16x64_i8(a2, bb, acc[2][nf], 0, 0, 0);
      acc[3][nf] = __builtin_amdgcn_mfma_i32_16x16x64_i8(a3, bb, acc[3][nf], 0, 0, 0);
    }
    __builtin_amdgcn_s_setprio(0);
    __syncthreads();                          // all waves done with Wl[step&1] (+ Xl at pos 8)

    if (pos == 8 && cc < 3) {                 // chunk boundary: restage X into the single buffer
      stage_x(xrow, (cc + 1) * 64, Xl, tid);
      __syncthreads();
    }
    if (++pos == 9) { pos = 0; ++cc; }
  }

  // ---- epilogue: out = acc * oscale[co]; C row = co (hi*4 + r4), col = spatial ----
#pragma unroll
  for (int mf = 0; mf < 4; ++mf) {
    const int cbase = wid * 64 + mf * 16 + hi * 4;
    const float4 os = *(const float4*)(oscale + cbase);
#pragma unroll
    for (int nf = 0; nf < 7; ++nf) {
      const int n_out = nf * 16 + col;
      const int r = n_out >= 56 ? 1 : 0;
      const int hrow = h0 + r;
      const int wcol = n_out - r * 56;
      float* o = out + ((((size_t)b * 256 + cbase) * 56 + hrow) * 56 + wcol);
      o[0 * 3136] = (float)acc[mf][nf][0] * os.x;
      o[1 * 3136] = (float)acc[mf][nf][1] * os.y;
      o[2 * 3136] = (float)acc[mf][nf][2] * os.z;
      o[3 * 3136] = (float)acc[mf][nf][3] * os.w;
    }
  }
}

// ---------------- Fallback: naive direct conv (if ws too small) ----------------------------
__global__ void conv_naive(const float* __restrict__ x, const float* __restrict__ w,
                           float* __restrict__ out, int total) {
  int idx = blockIdx.x * 256 + threadIdx.x;
  if (idx >= total) return;
  const int wc = idx % 56;
  int t = idx / 56;
  const int hr = t % 56; t /= 56;
  const int co = t % 256;
  const int b = t / 256;
  float acc = 0.f;
  for (int ci = 0; ci < 256; ++ci) {
    const float* xb = x + (((size_t)b * 256 + ci) * 56) * 56;
    const float* wb = w + ((size_t)co * 256 + ci) * 9;
#pragma unroll
    for (int kh = 0; kh < 3; ++kh) {
      const int hh = hr + kh - 1;
      if (hh < 0 || hh >= 56) continue;
#pragma unroll
      for (int kw = 0; kw < 3; ++kw) {
        const int ww = wc + kw - 1;
        if (ww < 0 || ww >= 56) continue;
        const float q = rintf(xb[hh * 56 + ww] * QSCALE) * D1;
        acc += q * wb[kh * 3 + kw];
      }
    }
  }
  out[idx] = acc;
}

extern "C" void kernel_launch(void* const* d_in, const int* in_sizes, int n_in,
                              void* d_out, int out_size, void* d_ws, size_t ws_size,
                              hipStream_t stream) {
  (void)in_sizes; (void)n_in; (void)out_size;
  const float* x = (const float*)d_in[0];
  const float* w = (const float*)d_in[1];
  float* out = (float*)d_out;

  if (ws_size < WS_NEED) {
    const int total = B_ * C_ * H_ * W_;
    conv_naive<<<(total + 255) / 256, 256, 0, stream>>>(x, w, out, total);
    return;
  }

  char* Xq = (char*)d_ws;
  char* Wt = (char*)d_ws + XQ_SPACE;
  float* oscale = (float*)((char*)d_ws + XQ_SPACE + WT_BYTES);

  quant_transpose_i8<<<dim3(56, 32), 256, 0, stream>>>(x, Xq);
  prep_weights_i8<<<dim3(256), 256, 0, stream>>>(w, Wt, oscale);
  conv_mfma_i8<<<dim3(896), 256, 0, stream>>>(Xq, Wt, oscale, out);
}

// Round 9
// 115.069 us; speedup vs baseline: 5.0780x; 1.0833x over previous
//
#include <hip/hip_runtime.h>

typedef int int32x4 __attribute__((ext_vector_type(4)));

#define B_ 32
#define C_ 256
#define H_ 56
#define W_ 56
#define HP 58
#define WP 58

static constexpr float QSCALE = 255.0f / 8.0f;   // 31.875 (exact); x<1 -> n in [0,32]
static constexpr float D1 = 8.0f / 255.0f;

// ws layout: [Xq i8 padded NHWC][slack][Wt i8 linear [step][co][ci]][oscale f32[256]]
static constexpr size_t XQ_BYTES = (size_t)B_ * HP * WP * C_;     // 27,541,504
static constexpr size_t XQ_SPACE = XQ_BYTES + 32768;
static constexpr size_t WT_BYTES = 36ull * 16384;                 // 589,824
static constexpr size_t WS_NEED = XQ_SPACE + WT_BYTES + 2048;

__device__ __forceinline__ void gload_lds16(const void* g, void* l) {
  __builtin_amdgcn_global_load_lds((const __attribute__((address_space(1))) unsigned int*)g,
                                   (__attribute__((address_space(3))) unsigned int*)l,
                                   16, 0, 0);
}

// ---------------- Kernel 1: quantize input + NCHW -> padded NHWC i8 (+ border zeroing) -----
__global__ __launch_bounds__(256) void quant_transpose_i8(const float* __restrict__ x,
                                                          char* __restrict__ Xq) {
  __shared__ unsigned short T[W_ * 256];     // integer level n per [w][c]
  const int h = blockIdx.x;                  // 0..55 -> padded row h+1
  const int b = blockIdx.y;
  const int c = threadIdx.x;

  const float4* src = (const float4*)(x + (((size_t)b * C_ + c) * H_ + h) * W_);
#pragma unroll
  for (int i = 0; i < 14; ++i) {
    float4 v = src[i];
    float vals[4] = {v.x, v.y, v.z, v.w};
    const int w0 = i * 4;
#pragma unroll
    for (int j = 0; j < 4; ++j) {
      int n = (int)rintf(vals[j] * QSCALE);
      n = n < 0 ? 0 : (n > 255 ? 255 : n);   // x<1 keeps n<=32; clamp for safety
      T[(w0 + j) * 256 + c] = (unsigned short)n;
    }
  }
  __syncthreads();

  char* row = Xq + (((size_t)b * HP + (h + 1)) * WP) * 256;
  // side border columns 0 and 57 of this padded row
  if (threadIdx.x < 64) {
    *(unsigned int*)(row + threadIdx.x * 4) = 0u;
    *(unsigned int*)(row + (size_t)57 * 256 + threadIdx.x * 4) = 0u;
  }
  // top/bottom padded rows (h==0 -> row 0, h==55 -> row 57)
  const int4 z4 = {0, 0, 0, 0};
  if (h == 0) {
    char* r0 = Xq + (((size_t)b * HP + 0) * WP) * 256;
    for (int i = threadIdx.x; i < WP * 16; i += 256) ((int4*)r0)[i] = z4;
  }
  if (h == 55) {
    char* r57 = Xq + (((size_t)b * HP + 57) * WP) * 256;
    for (int i = threadIdx.x; i < WP * 16; i += 256) ((int4*)r57)[i] = z4;
  }

  const int wid = threadIdx.x >> 6;
  const int lane = threadIdx.x & 63;
#pragma unroll
  for (int p = 0; p < 14; ++p) {
    const int w = p * 4 + wid;
    ushort4 v = *(const ushort4*)&T[w * 256 + lane * 4];
    unsigned int packed = (unsigned int)v.x | ((unsigned int)v.y << 8) |
                          ((unsigned int)v.z << 16) | ((unsigned int)v.w << 24);
    *(unsigned int*)(row + (size_t)(w + 1) * 256 + lane * 4) = packed;
  }
}

// ---------------- Kernel 2: fused absmax + i8 error-feedback quant, one block per c_out ----
// Wt layout (linear): Wt[(step*256 + co)*64 + (ci & 63)], step = (ci>>6)*9 + pos.
__global__ __launch_bounds__(256) void prep_weights_i8(const float* __restrict__ w,
                                                       char* __restrict__ Wt,
                                                       float* __restrict__ oscale) {
  __shared__ __align__(16) float wf[2304];
  __shared__ __align__(16) char Wq[2304];       // [chunk=cc*9+p][ci&63]
  __shared__ float red[4];
  __shared__ float sbc;
  const int co = blockIdx.x;
  const int tid = threadIdx.x;

  const float4* src = (const float4*)(w + (size_t)co * 2304);
  float m = 0.f;
  for (int i = tid; i < 576; i += 256) {
    float4 v = src[i];
    *(float4*)&wf[i * 4] = v;
    m = fmaxf(fmaxf(fabsf(v.x), fabsf(v.y)), fmaxf(fmaxf(fabsf(v.z), fabsf(v.w)), m));
  }

#pragma unroll
  for (int off = 32; off; off >>= 1) m = fmaxf(m, __shfl_down(m, off));
  if ((tid & 63) == 0) red[tid >> 6] = m;
  __syncthreads();
  if (tid == 0) {
    m = fmaxf(fmaxf(red[0], red[1]), fmaxf(red[2], red[3]));
    m = fmaxf(m, 1e-20f);
    sbc = m;
    oscale[co] = (m / 127.f) * D1;
  }
  __syncthreads();

  if (tid < 9) {
    const int p = tid;
    const float s = sbc / 127.f;
    const float inv = 1.f / s;
    float carry = 0.f;
    for (int ci = 0; ci < 256; ++ci) {
      float t = wf[ci * 9 + p] + carry;
      float qf = rintf(t * inv);
      qf = fminf(fmaxf(qf, -128.f), 127.f);
      carry = t - qf * s;
      Wq[((ci >> 6) * 9 + p) * 64 + (ci & 63)] = (char)(int)qf;
    }
  }
  __syncthreads();

  if (tid < 144) {
    const int chunk = tid >> 2;        // step = cc*9 + p
    const int g = tid & 3;             // 16B group
    int4 v = *(const int4*)&Wq[chunk * 64 + (g << 4)];
    *(int4*)(Wt + ((size_t)(chunk * 256 + co)) * 64 + (g << 4)) = v;
  }
}

// ---------------- X-tile staging: 4 padded rows x 58 cols x 64 ch, slot-swizzled source ----
__device__ __forceinline__ void stage_x(const char* __restrict__ xrow, int c0, char* dst, int tid) {
#pragma unroll
  for (int p = 0; p < 4; ++p) {
    const int s = p * 256 + tid;           // 1024 slots; rows 232..255 load in-ws garbage
    const int nin = s >> 2;
    const int cdat = (s & 3) ^ ((nin >> 1) & 3);
    gload_lds16(xrow + nin * 256 + c0 + cdat * 16, dst + s * 16);
  }
}

// ---------------- Kernel 3: implicit-GEMM conv, i8 MFMA 16x16x64 ---------------------------
// 4 waves. BM=256 co (4 m-frags/wave), BN=112 (2 rows, 7 n-frags). 36 steps of K=64.
// W: global->register, depth-2 prefetch (NO LDS). X: 16 KB LDS, restaged per ci-chunk.
__global__ __launch_bounds__(256) void conv_mfma_i8(const char* __restrict__ Xq,
                                                    const char* __restrict__ Wt,
                                                    const float* __restrict__ oscale,
                                                    float* __restrict__ out) {
  __shared__ __align__(16) char Xl[16384];
  const int tid = threadIdx.x;
  const int wid = tid >> 6, lane = tid & 63;
  const int col = lane & 15, hi = lane >> 4;

  // XCD-aware bijective swizzle: 896 blocks = 8 XCDs x 112
  const int l = blockIdx.x;
  const int wk = (l & 7) * 112 + (l >> 3);
  const int by = wk % 28;
  const int b = wk / 28;
  const int h0 = 2 * by;

  int nbase[7];
#pragma unroll
  for (int nf = 0; nf < 7; ++nf) {
    const int n_out = nf * 16 + col;
    const int r = n_out >= 56 ? 1 : 0;
    nbase[nf] = r * WP + (n_out - r * 56);
  }

  int32x4 acc[4][7];
#pragma unroll
  for (int mf = 0; mf < 4; ++mf)
#pragma unroll
    for (int nf = 0; nf < 7; ++nf) acc[mf][nf] = (int32x4){0, 0, 0, 0};

  const char* xrow = Xq + ((size_t)b * HP + h0) * WP * 256;
  // per-lane W base: step s frag mf at  wg + s*16384 + mf*1024  (1 KB contiguous per wave)
  const char* wg = Wt + (size_t)(wid * 4096 + col * 64 + hi * 16);

  int32x4 Wbuf[2][4];

  stage_x(xrow, 0, Xl, tid);
#pragma unroll
  for (int mf = 0; mf < 4; ++mf) Wbuf[0][mf] = *(const int32x4*)(wg + mf * 1024);
#pragma unroll
  for (int mf = 0; mf < 4; ++mf) Wbuf[1][mf] = *(const int32x4*)(wg + 16384 + mf * 1024);
  __syncthreads();

#pragma unroll 1
  for (int half = 0; half < 2; ++half) {
    const char* wgh = wg + (size_t)half * 18 * 16384;
#pragma unroll
    for (int s18 = 0; s18 < 18; ++s18) {
      const int par = s18 & 1;                    // compile-time after unroll
      const int pos = s18 % 9;
      const int kh = pos / 3, kw = pos % 3;
      const int poff = kh * WP + kw;

      __builtin_amdgcn_s_setprio(1);
#pragma unroll
      for (int nf = 0; nf < 7; ++nf) {
        const int nin = nbase[nf] + poff;
        int32x4 bb = *(const int32x4*)(Xl + nin * 64 + ((hi ^ ((nin >> 1) & 3)) << 4));
        acc[0][nf] = __builtin_amdgcn_mfma_i32_16x16x64_i8(Wbuf[par][0], bb, acc[0][nf], 0, 0, 0);
        acc[1][nf] = __builtin_amdgcn_mfma_i32_16x16x64_i8(Wbuf[par][1], bb, acc[1][nf], 0, 0, 0);
        acc[2][nf] = __builtin_amdgcn_mfma_i32_16x16x64_i8(Wbuf[par][2], bb, acc[2][nf], 0, 0, 0);
        acc[3][nf] = __builtin_amdgcn_mfma_i32_16x16x64_i8(Wbuf[par][3], bb, acc[3][nf], 0, 0, 0);
      }
      __builtin_amdgcn_s_setprio(0);

      // depth-2 W prefetch: step (half*18 + s18 + 2) into the buffer just consumed
      if (half == 0 || s18 < 16) {
        const char* wn = wgh + (size_t)(s18 + 2) * 16384;
#pragma unroll
        for (int mf = 0; mf < 4; ++mf) Wbuf[par][mf] = *(const int32x4*)(wn + mf * 1024);
      }

      // chunk boundary: restage X (barrier only here — 8 barriers total)
      if (pos == 8 && !(half == 1 && s18 == 17)) {
        const int ncc = half * 2 + (s18 / 9) + 1;
        __syncthreads();
        stage_x(xrow, ncc * 64, Xl, tid);
        __syncthreads();
      }
    }
  }

  // ---- epilogue: out = acc * oscale[co]; C row = co (hi*4 + r4), col = spatial ----
#pragma unroll
  for (int mf = 0; mf < 4; ++mf) {
    const int cbase = wid * 64 + mf * 16 + hi * 4;
    const float4 os = *(const float4*)(oscale + cbase);
#pragma unroll
    for (int nf = 0; nf < 7; ++nf) {
      const int n_out = nf * 16 + col;
      const int r = n_out >= 56 ? 1 : 0;
      const int hrow = h0 + r;
      const int wcol = n_out - r * 56;
      float* o = out + ((((size_t)b * 256 + cbase) * 56 + hrow) * 56 + wcol);
      o[0 * 3136] = (float)acc[mf][nf][0] * os.x;
      o[1 * 3136] = (float)acc[mf][nf][1] * os.y;
      o[2 * 3136] = (float)acc[mf][nf][2] * os.z;
      o[3 * 3136] = (float)acc[mf][nf][3] * os.w;
    }
  }
}

// ---------------- Fallback: naive direct conv (if ws too small) ----------------------------
__global__ void conv_naive(const float* __restrict__ x, const float* __restrict__ w,
                           float* __restrict__ out, int total) {
  int idx = blockIdx.x * 256 + threadIdx.x;
  if (idx >= total) return;
  const int wc = idx % 56;
  int t = idx / 56;
  const int hr = t % 56; t /= 56;
  const int co = t % 256;
  const int b = t / 256;
  float acc = 0.f;
  for (int ci = 0; ci < 256; ++ci) {
    const float* xb = x + (((size_t)b * 256 + ci) * 56) * 56;
    const float* wb = w + ((size_t)co * 256 + ci) * 9;
#pragma unroll
    for (int kh = 0; kh < 3; ++kh) {
      const int hh = hr + kh - 1;
      if (hh < 0 || hh >= 56) continue;
#pragma unroll
      for (int kw = 0; kw < 3; ++kw) {
        const int ww = wc + kw - 1;
        if (ww < 0 || ww >= 56) continue;
        const float q = rintf(xb[hh * 56 + ww] * QSCALE) * D1;
        acc += q * wb[kh * 3 + kw];
      }
    }
  }
  out[idx] = acc;
}

extern "C" void kernel_launch(void* const* d_in, const int* in_sizes, int n_in,
                              void* d_out, int out_size, void* d_ws, size_t ws_size,
                              hipStream_t stream) {
  (void)in_sizes; (void)n_in; (void)out_size;
  const float* x = (const float*)d_in[0];
  const float* w = (const float*)d_in[1];
  float* out = (float*)d_out;

  if (ws_size < WS_NEED) {
    const int total = B_ * C_ * H_ * W_;
    conv_naive<<<(total + 255) / 256, 256, 0, stream>>>(x, w, out, total);
    return;
  }

  char* Xq = (char*)d_ws;
  char* Wt = (char*)d_ws + XQ_SPACE;
  float* oscale = (float*)((char*)d_ws + XQ_SPACE + WT_BYTES);

  quant_transpose_i8<<<dim3(56, 32), 256, 0, stream>>>(x, Xq);
  prep_weights_i8<<<dim3(256), 256, 0, stream>>>(w, Wt, oscale);
  conv_mfma_i8<<<dim3(896), 256, 0, stream>>>(Xq, Wt, oscale, out);
}

// Round 10
// 107.047 us; speedup vs baseline: 5.4585x; 1.0749x over previous
//
#include <hip/hip_runtime.h>

typedef int int32x4 __attribute__((ext_vector_type(4)));

#define B_ 32
#define C_ 256
#define H_ 56
#define W_ 56
#define HP 58
#define WP 58

static constexpr float QSCALE = 255.0f / 8.0f;   // 31.875 (exact); x<1 -> n in [0,32]
static constexpr float D1 = 8.0f / 255.0f;

// ws layout: [Xq i8 padded NHWC][slack][Wt i8 linear [step][co][ci]][oscale f32[256]]
static constexpr size_t XQ_BYTES = (size_t)B_ * HP * WP * C_;     // 27,541,504
static constexpr size_t XQ_SPACE = XQ_BYTES + 32768;
static constexpr size_t WT_BYTES = 36ull * 16384;                 // 589,824
static constexpr size_t WS_NEED = XQ_SPACE + WT_BYTES + 2048;

__device__ __forceinline__ void gload_lds16(const void* g, void* l) {
  __builtin_amdgcn_global_load_lds((const __attribute__((address_space(1))) unsigned int*)g,
                                   (__attribute__((address_space(3))) unsigned int*)l,
                                   16, 0, 0);
}

// ---------------- Kernel 1: quantize input + NCHW -> padded NHWC i8 (+ border zeroing) -----
__global__ __launch_bounds__(256) void quant_transpose_i8(const float* __restrict__ x,
                                                          char* __restrict__ Xq) {
  __shared__ unsigned short T[W_ * 256];     // integer level n per [w][c]
  const int h = blockIdx.x;                  // 0..55 -> padded row h+1
  const int b = blockIdx.y;
  const int c = threadIdx.x;

  const float4* src = (const float4*)(x + (((size_t)b * C_ + c) * H_ + h) * W_);
#pragma unroll
  for (int i = 0; i < 14; ++i) {
    float4 v = src[i];
    float vals[4] = {v.x, v.y, v.z, v.w};
    const int w0 = i * 4;
#pragma unroll
    for (int j = 0; j < 4; ++j) {
      int n = (int)rintf(vals[j] * QSCALE);
      n = n < 0 ? 0 : (n > 255 ? 255 : n);   // x<1 keeps n<=32; clamp for safety
      T[(w0 + j) * 256 + c] = (unsigned short)n;
    }
  }
  __syncthreads();

  char* row = Xq + (((size_t)b * HP + (h + 1)) * WP) * 256;
  // side border columns 0 and 57 of this padded row
  if (threadIdx.x < 64) {
    *(unsigned int*)(row + threadIdx.x * 4) = 0u;
    *(unsigned int*)(row + (size_t)57 * 256 + threadIdx.x * 4) = 0u;
  }
  // top/bottom padded rows (h==0 -> row 0, h==55 -> row 57)
  const int4 z4 = {0, 0, 0, 0};
  if (h == 0) {
    char* r0 = Xq + (((size_t)b * HP + 0) * WP) * 256;
    for (int i = threadIdx.x; i < WP * 16; i += 256) ((int4*)r0)[i] = z4;
  }
  if (h == 55) {
    char* r57 = Xq + (((size_t)b * HP + 57) * WP) * 256;
    for (int i = threadIdx.x; i < WP * 16; i += 256) ((int4*)r57)[i] = z4;
  }

  const int wid = threadIdx.x >> 6;
  const int lane = threadIdx.x & 63;
#pragma unroll
  for (int p = 0; p < 14; ++p) {
    const int w = p * 4 + wid;
    ushort4 v = *(const ushort4*)&T[w * 256 + lane * 4];
    unsigned int packed = (unsigned int)v.x | ((unsigned int)v.y << 8) |
                          ((unsigned int)v.z << 16) | ((unsigned int)v.w << 24);
    *(unsigned int*)(row + (size_t)(w + 1) * 256 + lane * 4) = packed;
  }
}

// ---------------- Kernel 2: fused absmax + i8 error-feedback quant, one block per c_out ----
// Wt layout (linear): Wt[(step*256 + co)*64 + (ci & 63)], step = (ci>>6)*9 + pos.
__global__ __launch_bounds__(256) void prep_weights_i8(const float* __restrict__ w,
                                                       char* __restrict__ Wt,
                                                       float* __restrict__ oscale) {
  __shared__ __align__(16) float wf[2304];
  __shared__ __align__(16) char Wq[2304];       // [chunk=cc*9+p][ci&63]
  __shared__ float red[4];
  __shared__ float sbc;
  const int co = blockIdx.x;
  const int tid = threadIdx.x;

  const float4* src = (const float4*)(w + (size_t)co * 2304);
  float m = 0.f;
  for (int i = tid; i < 576; i += 256) {
    float4 v = src[i];
    *(float4*)&wf[i * 4] = v;
    m = fmaxf(fmaxf(fabsf(v.x), fabsf(v.y)), fmaxf(fmaxf(fabsf(v.z), fabsf(v.w)), m));
  }

#pragma unroll
  for (int off = 32; off; off >>= 1) m = fmaxf(m, __shfl_down(m, off));
  if ((tid & 63) == 0) red[tid >> 6] = m;
  __syncthreads();
  if (tid == 0) {
    m = fmaxf(fmaxf(red[0], red[1]), fmaxf(red[2], red[3]));
    m = fmaxf(m, 1e-20f);
    sbc = m;
    oscale[co] = (m / 127.f) * D1;
  }
  __syncthreads();

  if (tid < 9) {
    const int p = tid;
    const float s = sbc / 127.f;
    const float inv = 1.f / s;
    float carry = 0.f;
    for (int ci = 0; ci < 256; ++ci) {
      float t = wf[ci * 9 + p] + carry;
      float qf = rintf(t * inv);
      qf = fminf(fmaxf(qf, -128.f), 127.f);
      carry = t - qf * s;
      Wq[((ci >> 6) * 9 + p) * 64 + (ci & 63)] = (char)(int)qf;
    }
  }
  __syncthreads();

  if (tid < 144) {
    const int chunk = tid >> 2;        // step = cc*9 + p
    const int g = tid & 3;             // 16B group
    int4 v = *(const int4*)&Wq[chunk * 64 + (g << 4)];
    *(int4*)(Wt + ((size_t)(chunk * 256 + co)) * 64 + (g << 4)) = v;
  }
}

// ---------------- X staging: one 256-lane pass (p = 0..3) of a 16 KB chunk tile ------------
__device__ __forceinline__ void stage_pass(const char* __restrict__ xrow, int c0, char* dst,
                                           int p, int tid) {
  const int s = p * 256 + tid;             // 16B slot; rows 232..255 read in-ws slack
  const int nin = s >> 2;
  const int cdat = (s & 3) ^ ((nin >> 1) & 3);
  gload_lds16(xrow + nin * 256 + c0 + cdat * 16, dst + s * 16);
}

// ---------------- Kernel 3: implicit-GEMM conv, i8 MFMA 16x16x64 ---------------------------
// 4 waves. BM=256 co (4 m-frags/wave), BN=112 (2 rows, 7 n-frags). 36 steps of K=64.
// W: global->register, named depth-2 buffers (WA/WB). X: 2x16KB LDS, 1 barrier per chunk.
__global__ __launch_bounds__(256, 2) void conv_mfma_i8(const char* __restrict__ Xq,
                                                       const char* __restrict__ Wt,
                                                       const float* __restrict__ oscale,
                                                       float* __restrict__ out) {
  __shared__ __align__(16) char Xl[2][16384];
  const int tid = threadIdx.x;
  const int wid = tid >> 6, lane = tid & 63;
  const int col = lane & 15, hi = lane >> 4;

  // XCD-aware bijective swizzle: 896 blocks = 8 XCDs x 112
  const int l = blockIdx.x;
  const int wk = (l & 7) * 112 + (l >> 3);
  const int by = wk % 28;
  const int b = wk / 28;
  const int h0 = 2 * by;

  int nbase[7];
#pragma unroll
  for (int nf = 0; nf < 7; ++nf) {
    const int n_out = nf * 16 + col;
    const int r = n_out >= 56 ? 1 : 0;
    nbase[nf] = r * WP + (n_out - r * 56);
  }

  int32x4 acc[4][7];
#pragma unroll
  for (int mf = 0; mf < 4; ++mf)
#pragma unroll
    for (int nf = 0; nf < 7; ++nf) acc[mf][nf] = (int32x4){0, 0, 0, 0};

  const char* xrow = Xq + ((size_t)b * HP + h0) * WP * 256;
  const char* wg = Wt + (size_t)(wid * 4096 + col * 64 + hi * 16);

  // prologue: stage chunk 0, load W steps 0 and 1 into named register buffers
  stage_pass(xrow, 0, Xl[0], 0, tid);
  stage_pass(xrow, 0, Xl[0], 1, tid);
  stage_pass(xrow, 0, Xl[0], 2, tid);
  stage_pass(xrow, 0, Xl[0], 3, tid);
  int32x4 WA0 = *(const int32x4*)(wg);
  int32x4 WA1 = *(const int32x4*)(wg + 1024);
  int32x4 WA2 = *(const int32x4*)(wg + 2048);
  int32x4 WA3 = *(const int32x4*)(wg + 3072);
  int32x4 WB0 = *(const int32x4*)(wg + 16384);
  int32x4 WB1 = *(const int32x4*)(wg + 16384 + 1024);
  int32x4 WB2 = *(const int32x4*)(wg + 16384 + 2048);
  int32x4 WB3 = *(const int32x4*)(wg + 16384 + 3072);
  const char* wpA = wg + 2 * 16384;
  const char* wpB = wg + 3 * 16384;
  __syncthreads();

#define CSTEP(W0_, W1_, W2_, W3_, pos_, xoff_)                                            \
  {                                                                                       \
    const int kh_ = ((pos_)*11) >> 5;                                                     \
    const int prow_ = kh_ * WP + ((pos_)-3 * kh_);                                        \
    __builtin_amdgcn_s_setprio(1);                                                        \
    _Pragma("unroll") for (int nf = 0; nf < 7; ++nf) {                                    \
      const int nin = nbase[nf] + prow_;                                                  \
      const char* ba =                                                                    \
          (const char*)Xl + (xoff_) + nin * 64 + ((hi ^ ((nin >> 1) & 3)) << 4);          \
      int32x4 bb = *(const int32x4*)ba;                                                   \
      acc[0][nf] = __builtin_amdgcn_mfma_i32_16x16x64_i8(W0_, bb, acc[0][nf], 0, 0, 0);   \
      acc[1][nf] = __builtin_amdgcn_mfma_i32_16x16x64_i8(W1_, bb, acc[1][nf], 0, 0, 0);   \
      acc[2][nf] = __builtin_amdgcn_mfma_i32_16x16x64_i8(W2_, bb, acc[2][nf], 0, 0, 0);   \
      acc[3][nf] = __builtin_amdgcn_mfma_i32_16x16x64_i8(W3_, bb, acc[3][nf], 0, 0, 0);   \
    }                                                                                     \
    __builtin_amdgcn_s_setprio(0);                                                        \
  }

  int posA = 0, ccA = 0, xoffA = 0;
#pragma unroll 1
  for (int it = 0; it < 18; ++it) {
    // ---------------- step A (global step 2*it) ----------------
    if (ccA < 3 && posA < 4) stage_pass(xrow, (ccA + 1) * 64, Xl[(ccA + 1) & 1], posA, tid);
    CSTEP(WA0, WA1, WA2, WA3, posA, xoffA);
    if (it < 17) {
      WA0 = *(const int32x4*)(wpA);
      WA1 = *(const int32x4*)(wpA + 1024);
      WA2 = *(const int32x4*)(wpA + 2048);
      WA3 = *(const int32x4*)(wpA + 3072);
      wpA += 32768;
    }
    if (posA == 8 && ccA < 3) __syncthreads();

    // ---------------- step B (global step 2*it+1) ----------------
    int posB = posA + 1, ccB = ccA, xoffB = xoffA;
    if (posB == 9) { posB = 0; ccB = ccA + 1; xoffB ^= 16384; }

    if (ccB < 3 && posB < 4) stage_pass(xrow, (ccB + 1) * 64, Xl[(ccB + 1) & 1], posB, tid);
    CSTEP(WB0, WB1, WB2, WB3, posB, xoffB);
    if (it < 17) {
      WB0 = *(const int32x4*)(wpB);
      WB1 = *(const int32x4*)(wpB + 1024);
      WB2 = *(const int32x4*)(wpB + 2048);
      WB3 = *(const int32x4*)(wpB + 3072);
      wpB += 32768;
    }
    if (posB == 8 && ccB < 3) __syncthreads();

    // advance to next step-A indices
    posA = posB + 1; ccA = ccB; xoffA = xoffB;
    if (posA == 9) { posA = 0; ccA = ccB + 1; xoffA ^= 16384; }
  }
#undef CSTEP

  // ---- epilogue: out = acc * oscale[co]; C row = co (hi*4 + r4), col = spatial ----
#pragma unroll
  for (int mf = 0; mf < 4; ++mf) {
    const int cbase = wid * 64 + mf * 16 + hi * 4;
    const float4 os = *(const float4*)(oscale + cbase);
#pragma unroll
    for (int nf = 0; nf < 7; ++nf) {
      const int n_out = nf * 16 + col;
      const int r = n_out >= 56 ? 1 : 0;
      const int hrow = h0 + r;
      const int wcol = n_out - r * 56;
      float* o = out + ((((size_t)b * 256 + cbase) * 56 + hrow) * 56 + wcol);
      o[0 * 3136] = (float)acc[mf][nf][0] * os.x;
      o[1 * 3136] = (float)acc[mf][nf][1] * os.y;
      o[2 * 3136] = (float)acc[mf][nf][2] * os.z;
      o[3 * 3136] = (float)acc[mf][nf][3] * os.w;
    }
  }
}

// ---------------- Fallback: naive direct conv (if ws too small) ----------------------------
__global__ void conv_naive(const float* __restrict__ x, const float* __restrict__ w,
                           float* __restrict__ out, int total) {
  int idx = blockIdx.x * 256 + threadIdx.x;
  if (idx >= total) return;
  const int wc = idx % 56;
  int t = idx / 56;
  const int hr = t % 56; t /= 56;
  const int co = t % 256;
  const int b = t / 256;
  float acc = 0.f;
  for (int ci = 0; ci < 256; ++ci) {
    const float* xb = x + (((size_t)b * 256 + ci) * 56) * 56;
    const float* wb = w + ((size_t)co * 256 + ci) * 9;
#pragma unroll
    for (int kh = 0; kh < 3; ++kh) {
      const int hh = hr + kh - 1;
      if (hh < 0 || hh >= 56) continue;
#pragma unroll
      for (int kw = 0; kw < 3; ++kw) {
        const int ww = wc + kw - 1;
        if (ww < 0 || ww >= 56) continue;
        const float q = rintf(xb[hh * 56 + ww] * QSCALE) * D1;
        acc += q * wb[kh * 3 + kw];
      }
    }
  }
  out[idx] = acc;
}

extern "C" void kernel_launch(void* const* d_in, const int* in_sizes, int n_in,
                              void* d_out, int out_size, void* d_ws, size_t ws_size,
                              hipStream_t stream) {
  (void)in_sizes; (void)n_in; (void)out_size;
  const float* x = (const float*)d_in[0];
  const float* w = (const float*)d_in[1];
  float* out = (float*)d_out;

  if (ws_size < WS_NEED) {
    const int total = B_ * C_ * H_ * W_;
    conv_naive<<<(total + 255) / 256, 256, 0, stream>>>(x, w, out, total);
    return;
  }

  char* Xq = (char*)d_ws;
  char* Wt = (char*)d_ws + XQ_SPACE;
  float* oscale = (float*)((char*)d_ws + XQ_SPACE + WT_BYTES);

  quant_transpose_i8<<<dim3(56, 32), 256, 0, stream>>>(x, Xq);
  prep_weights_i8<<<dim3(256), 256, 0, stream>>>(w, Wt, oscale);
  conv_mfma_i8<<<dim3(896), 256, 0, stream>>>(Xq, Wt, oscale, out);
}

// Round 11
// 102.200 us; speedup vs baseline: 5.7174x; 1.0474x over previous
//
#include <hip/hip_runtime.h>

typedef int int32x4 __attribute__((ext_vector_type(4)));

#define B_ 32
#define C_ 256
#define H_ 56
#define W_ 56
#define HP 58
#define WP 58

static constexpr float QSCALE = 255.0f / 8.0f;   // 31.875 (exact); x<1 -> n in [0,32]
static constexpr float D1 = 8.0f / 255.0f;

// ws layout: [Xq i8 padded NHWC][slack][Wt i8 linear [step][co][ci], padded to 38 steps][oscale]
static constexpr size_t XQ_BYTES = (size_t)B_ * HP * WP * C_;     // 27,541,504
static constexpr size_t XQ_SPACE = XQ_BYTES + 32768;
static constexpr size_t WT_SPACE = 38ull * 16384;                 // 622,592 (36 used + 2 pad)
static constexpr size_t WS_NEED = XQ_SPACE + WT_SPACE + 2048;

#define XROW 3728        // LDS row stride bytes (233 slots of 16B; 233%8=1 -> bank-even)
#define XBUF (4 * XROW)  // one chunk buffer: 14,912 B

// ---------------- Kernel 1: quantize input + NCHW -> padded NHWC i8 (+ border zeroing) -----
__global__ __launch_bounds__(256) void quant_transpose_i8(const float* __restrict__ x,
                                                          char* __restrict__ Xq) {
  __shared__ unsigned short T[W_ * 256];     // integer level n per [w][c]
  const int h = blockIdx.x;                  // 0..55 -> padded row h+1
  const int b = blockIdx.y;
  const int c = threadIdx.x;

  const float4* src = (const float4*)(x + (((size_t)b * C_ + c) * H_ + h) * W_);
#pragma unroll
  for (int i = 0; i < 14; ++i) {
    float4 v = src[i];
    float vals[4] = {v.x, v.y, v.z, v.w};
    const int w0 = i * 4;
#pragma unroll
    for (int j = 0; j < 4; ++j) {
      int n = (int)rintf(vals[j] * QSCALE);
      n = n < 0 ? 0 : (n > 255 ? 255 : n);   // x<1 keeps n<=32; clamp for safety
      T[(w0 + j) * 256 + c] = (unsigned short)n;
    }
  }
  __syncthreads();

  char* row = Xq + (((size_t)b * HP + (h + 1)) * WP) * 256;
  // side border columns 0 and 57 of this padded row
  if (threadIdx.x < 64) {
    *(unsigned int*)(row + threadIdx.x * 4) = 0u;
    *(unsigned int*)(row + (size_t)57 * 256 + threadIdx.x * 4) = 0u;
  }
  // top/bottom padded rows (h==0 -> row 0, h==55 -> row 57)
  const int4 z4 = {0, 0, 0, 0};
  if (h == 0) {
    char* r0 = Xq + (((size_t)b * HP + 0) * WP) * 256;
    for (int i = threadIdx.x; i < WP * 16; i += 256) ((int4*)r0)[i] = z4;
  }
  if (h == 55) {
    char* r57 = Xq + (((size_t)b * HP + 57) * WP) * 256;
    for (int i = threadIdx.x; i < WP * 16; i += 256) ((int4*)r57)[i] = z4;
  }

  const int wid = threadIdx.x >> 6;
  const int lane = threadIdx.x & 63;
#pragma unroll
  for (int p = 0; p < 14; ++p) {
    const int w = p * 4 + wid;
    ushort4 v = *(const ushort4*)&T[w * 256 + lane * 4];
    unsigned int packed = (unsigned int)v.x | ((unsigned int)v.y << 8) |
                          ((unsigned int)v.z << 16) | ((unsigned int)v.w << 24);
    *(unsigned int*)(row + (size_t)(w + 1) * 256 + lane * 4) = packed;
  }
}

// ---------------- Kernel 2: fused absmax + i8 error-feedback quant, one block per c_out ----
// Wt layout (linear): Wt[(step*256 + co)*64 + (ci & 63)], step = (ci>>6)*9 + pos.
__global__ __launch_bounds__(256) void prep_weights_i8(const float* __restrict__ w,
                                                       char* __restrict__ Wt,
                                                       float* __restrict__ oscale) {
  __shared__ __align__(16) float wf[2304];
  __shared__ __align__(16) char Wq[2304];       // [chunk=cc*9+p][ci&63]
  __shared__ float red[4];
  __shared__ float sbc;
  const int co = blockIdx.x;
  const int tid = threadIdx.x;

  const float4* src = (const float4*)(w + (size_t)co * 2304);
  float m = 0.f;
  for (int i = tid; i < 576; i += 256) {
    float4 v = src[i];
    *(float4*)&wf[i * 4] = v;
    m = fmaxf(fmaxf(fabsf(v.x), fabsf(v.y)), fmaxf(fmaxf(fabsf(v.z), fabsf(v.w)), m));
  }

#pragma unroll
  for (int off = 32; off; off >>= 1) m = fmaxf(m, __shfl_down(m, off));
  if ((tid & 63) == 0) red[tid >> 6] = m;
  __syncthreads();
  if (tid == 0) {
    m = fmaxf(fmaxf(red[0], red[1]), fmaxf(red[2], red[3]));
    m = fmaxf(m, 1e-20f);
    sbc = m;
    oscale[co] = (m / 127.f) * D1;
  }
  __syncthreads();

  if (tid < 9) {
    const int p = tid;
    const float s = sbc / 127.f;
    const float inv = 1.f / s;
    float carry = 0.f;
    for (int ci = 0; ci < 256; ++ci) {
      float t = wf[ci * 9 + p] + carry;
      float qf = rintf(t * inv);
      qf = fminf(fmaxf(qf, -128.f), 127.f);
      carry = t - qf * s;
      Wq[((ci >> 6) * 9 + p) * 64 + (ci & 63)] = (char)(int)qf;
    }
  }
  __syncthreads();

  if (tid < 144) {
    const int chunk = tid >> 2;        // step = cc*9 + p
    const int g = tid & 3;             // 16B group
    int4 v = *(const int4*)&Wq[chunk * 64 + (g << 4)];
    *(int4*)(Wt + ((size_t)(chunk * 256 + co)) * 64 + (g << 4)) = v;
  }
}

// ---------------- Kernel 3: implicit-GEMM conv, i8 MFMA 16x16x64 ---------------------------
// 4 waves. BM=256 co (4 m-frags/wave), BN=112 (2 rows, 7 n-frags). 36 steps of K=64.
// W: global->named-reg depth-2. X: ci-group-major LDS [hi][nin], stride 3728 -> B-reads are
// pure base+immediate (zero per-step VALU). Reg-staged X (loads pos0-3, writes pos4-7).
__global__ __launch_bounds__(256, 2) void conv_mfma_i8(const char* __restrict__ Xq,
                                                       const char* __restrict__ Wt,
                                                       const float* __restrict__ oscale,
                                                       float* __restrict__ out) {
  __shared__ __align__(16) char Xl[2][XBUF];     // 29,824 B
  const int tid = threadIdx.x;
  const int wid = tid >> 6, lane = tid & 63;
  const int col = lane & 15, hi = lane >> 4;

  // XCD-aware bijective swizzle: 896 blocks = 8 XCDs x 112
  const int l = blockIdx.x;
  const int wk = (l & 7) * 112 + (l >> 3);
  const int by = wk % 28;
  const int b = wk / 28;
  const int h0 = 2 * by;

  int banf[7];
#pragma unroll
  for (int nf = 0; nf < 7; ++nf) {
    const int n_out = nf * 16 + col;
    const int r = n_out >= 56 ? 1 : 0;
    banf[nf] = hi * XROW + (r * WP + (n_out - r * 56)) * 16;
  }

  int32x4 acc[4][7];
#pragma unroll
  for (int mf = 0; mf < 4; ++mf)
#pragma unroll
    for (int nf = 0; nf < 7; ++nf) acc[mf][nf] = (int32x4){0, 0, 0, 0};

  const char* xrow = Xq + ((size_t)b * HP + h0) * WP * 256;
  const char* wg = Wt + (size_t)(wid * 4096 + col * 64 + hi * 16);
  char* XlB = (char*)Xl;

  int32x4 Wc0, Wc1, Wc2, Wc3, Wn0, Wn1, Wn2, Wn3;
  int32x4 sr0, sr1, sr2, sr3;

  // ---- prologue: load+write X chunk 0, load W steps 0,1 ----
  { const int s = tid;       sr0 = *(const int32x4*)(xrow + (s >> 2) * 256 + (s & 3) * 16); }
  { const int s = 256 + tid; sr1 = *(const int32x4*)(xrow + (s >> 2) * 256 + (s & 3) * 16); }
  { const int s = 512 + tid; sr2 = *(const int32x4*)(xrow + (s >> 2) * 256 + (s & 3) * 16); }
  if (tid < 160) { const int s = 768 + tid;
                   sr3 = *(const int32x4*)(xrow + (s >> 2) * 256 + (s & 3) * 16); }
  Wc0 = *(const int32x4*)(wg);
  Wc1 = *(const int32x4*)(wg + 1024);
  Wc2 = *(const int32x4*)(wg + 2048);
  Wc3 = *(const int32x4*)(wg + 3072);
  Wn0 = *(const int32x4*)(wg + 16384);
  Wn1 = *(const int32x4*)(wg + 16384 + 1024);
  Wn2 = *(const int32x4*)(wg + 16384 + 2048);
  Wn3 = *(const int32x4*)(wg + 16384 + 3072);
  { const int s = tid;       *(int32x4*)(XlB + (s & 3) * XROW + (s >> 2) * 16) = sr0; }
  { const int s = 256 + tid; *(int32x4*)(XlB + (s & 3) * XROW + (s >> 2) * 16) = sr1; }
  { const int s = 512 + tid; *(int32x4*)(XlB + (s & 3) * XROW + (s >> 2) * 16) = sr2; }
  if (tid < 160) { const int s = 768 + tid;
                   *(int32x4*)(XlB + (s & 3) * XROW + (s >> 2) * 16) = sr3; }
  __syncthreads();

#define MSTEP(POS, PROW16)                                                               \
  {                                                                                      \
    __builtin_amdgcn_s_setprio(1);                                                       \
    _Pragma("unroll") for (int nf = 0; nf < 7; ++nf) {                                   \
      int32x4 bb = *(const int32x4*)(XlB + bx[nf] + (PROW16));                           \
      acc[0][nf] = __builtin_amdgcn_mfma_i32_16x16x64_i8(Wc0, bb, acc[0][nf], 0, 0, 0);  \
      acc[1][nf] = __builtin_amdgcn_mfma_i32_16x16x64_i8(Wc1, bb, acc[1][nf], 0, 0, 0);  \
      acc[2][nf] = __builtin_amdgcn_mfma_i32_16x16x64_i8(Wc2, bb, acc[2][nf], 0, 0, 0);  \
      acc[3][nf] = __builtin_amdgcn_mfma_i32_16x16x64_i8(Wc3, bb, acc[3][nf], 0, 0, 0);  \
    }                                                                                    \
    __builtin_amdgcn_s_setprio(0);                                                       \
    Wc0 = Wn0; Wc1 = Wn1; Wc2 = Wn2; Wc3 = Wn3;                                          \
    Wn0 = *(const int32x4*)(wgcc + ((POS) + 2) * 16384);                                 \
    Wn1 = *(const int32x4*)(wgcc + ((POS) + 2) * 16384 + 1024);                          \
    Wn2 = *(const int32x4*)(wgcc + ((POS) + 2) * 16384 + 2048);                          \
    Wn3 = *(const int32x4*)(wgcc + ((POS) + 2) * 16384 + 3072);                          \
  }

  const char* wgcc = wg;
#pragma unroll 1
  for (int cc = 0; cc < 4; ++cc) {
    const bool st = (cc < 3);
    const char* xsrc = xrow + (cc + 1) * 64;
    char* xnxt = XlB + ((cc & 1) ^ 1) * XBUF;
    int bx[7];
#pragma unroll
    for (int nf = 0; nf < 7; ++nf) bx[nf] = banf[nf] + (cc & 1) * XBUF;

    if (st) { const int s = tid;       sr0 = *(const int32x4*)(xsrc + (s >> 2) * 256 + (s & 3) * 16); }
    MSTEP(0, 0)
    if (st) { const int s = 256 + tid; sr1 = *(const int32x4*)(xsrc + (s >> 2) * 256 + (s & 3) * 16); }
    MSTEP(1, 16)
    if (st) { const int s = 512 + tid; sr2 = *(const int32x4*)(xsrc + (s >> 2) * 256 + (s & 3) * 16); }
    MSTEP(2, 32)
    if (st && tid < 160) { const int s = 768 + tid;
                           sr3 = *(const int32x4*)(xsrc + (s >> 2) * 256 + (s & 3) * 16); }
    MSTEP(3, 928)
    if (st) { const int s = tid;       *(int32x4*)(xnxt + (s & 3) * XROW + (s >> 2) * 16) = sr0; }
    MSTEP(4, 944)
    if (st) { const int s = 256 + tid; *(int32x4*)(xnxt + (s & 3) * XROW + (s >> 2) * 16) = sr1; }
    MSTEP(5, 960)
    if (st) { const int s = 512 + tid; *(int32x4*)(xnxt + (s & 3) * XROW + (s >> 2) * 16) = sr2; }
    MSTEP(6, 1856)
    if (st && tid < 160) { const int s = 768 + tid;
                           *(int32x4*)(xnxt + (s & 3) * XROW + (s >> 2) * 16) = sr3; }
    MSTEP(7, 1872)
    MSTEP(8, 1888)
    if (st) __syncthreads();
    wgcc += 9 * 16384;
  }
#undef MSTEP

  // ---- epilogue: out = acc * oscale[co]; C row = co (hi*4 + r4), col = spatial ----
#pragma unroll
  for (int mf = 0; mf < 4; ++mf) {
    const int cbase = wid * 64 + mf * 16 + hi * 4;
    const float4 os = *(const float4*)(oscale + cbase);
#pragma unroll
    for (int nf = 0; nf < 7; ++nf) {
      const int n_out = nf * 16 + col;
      const int r = n_out >= 56 ? 1 : 0;
      const int hrow = h0 + r;
      const int wcol = n_out - r * 56;
      float* o = out + ((((size_t)b * 256 + cbase) * 56 + hrow) * 56 + wcol);
      o[0 * 3136] = (float)acc[mf][nf][0] * os.x;
      o[1 * 3136] = (float)acc[mf][nf][1] * os.y;
      o[2 * 3136] = (float)acc[mf][nf][2] * os.z;
      o[3 * 3136] = (float)acc[mf][nf][3] * os.w;
    }
  }
}

// ---------------- Fallback: naive direct conv (if ws too small) ----------------------------
__global__ void conv_naive(const float* __restrict__ x, const float* __restrict__ w,
                           float* __restrict__ out, int total) {
  int idx = blockIdx.x * 256 + threadIdx.x;
  if (idx >= total) return;
  const int wc = idx % 56;
  int t = idx / 56;
  const int hr = t % 56; t /= 56;
  const int co = t % 256;
  const int b = t / 256;
  float acc = 0.f;
  for (int ci = 0; ci < 256; ++ci) {
    const float* xb = x + (((size_t)b * 256 + ci) * 56) * 56;
    const float* wb = w + ((size_t)co * 256 + ci) * 9;
#pragma unroll
    for (int kh = 0; kh < 3; ++kh) {
      const int hh = hr + kh - 1;
      if (hh < 0 || hh >= 56) continue;
#pragma unroll
      for (int kw = 0; kw < 3; ++kw) {
        const int ww = wc + kw - 1;
        if (ww < 0 || ww >= 56) continue;
        const float q = rintf(xb[hh * 56 + ww] * QSCALE) * D1;
        acc += q * wb[kh * 3 + kw];
      }
    }
  }
  out[idx] = acc;
}

extern "C" void kernel_launch(void* const* d_in, const int* in_sizes, int n_in,
                              void* d_out, int out_size, void* d_ws, size_t ws_size,
                              hipStream_t stream) {
  (void)in_sizes; (void)n_in; (void)out_size;
  const float* x = (const float*)d_in[0];
  const float* w = (const float*)d_in[1];
  float* out = (float*)d_out;

  if (ws_size < WS_NEED) {
    const int total = B_ * C_ * H_ * W_;
    conv_naive<<<(total + 255) / 256, 256, 0, stream>>>(x, w, out, total);
    return;
  }

  char* Xq = (char*)d_ws;
  char* Wt = (char*)d_ws + XQ_SPACE;
  float* oscale = (float*)((char*)d_ws + XQ_SPACE + WT_SPACE);

  quant_transpose_i8<<<dim3(56, 32), 256, 0, stream>>>(x, Xq);
  prep_weights_i8<<<dim3(256), 256, 0, stream>>>(w, Wt, oscale);
  conv_mfma_i8<<<dim3(896), 256, 0, stream>>>(Xq, Wt, oscale, out);
}

// Round 13
// 94.000 us; speedup vs baseline: 6.2162x; 1.0872x over previous
//
#include <hip/hip_runtime.h>

typedef int int32x4 __attribute__((ext_vector_type(4)));

#define B_ 32
#define C_ 256
#define H_ 56
#define W_ 56

static constexpr float QSCALE = 255.0f / 8.0f;   // 31.875 (exact); x<1 -> n in [0,32]
static constexpr float D1 = 8.0f / 255.0f;

// Xq global layout: [b][cig 0..15][h 0..57][w 0..57][ci16] -- per-cig plane is linear,
// so a chunk tile (4 rows x 58 w x 16 ci per cig) is 4 contiguous 3712B spans.
#define PLANE 53824          // 58*58*16
#define BSTR  861184         // 16 * PLANE
static constexpr size_t XQ_BYTES = (size_t)B_ * BSTR;             // 27,541,504
static constexpr size_t XQ_SPACE = XQ_BYTES + 32768;
static constexpr size_t WT_SPACE = 38ull * 16384;                 // 36 steps + 2 pad
static constexpr size_t WS_NEED = XQ_SPACE + WT_SPACE + 2048;

#define XROWB 3712           // LDS stride per ci-group (232 x 16B)
#define XBUFB 14848          // one chunk buffer (4 groups)

__device__ __forceinline__ void gload_lds16(const void* g, void* l) {
  __builtin_amdgcn_global_load_lds((const __attribute__((address_space(1))) unsigned int*)g,
                                   (__attribute__((address_space(3))) unsigned int*)l,
                                   16, 0, 0);
}

// ---------------- Kernel 1: quantize input + NCHW -> [b][cig][h][w][ci16] i8 ---------------
__global__ __launch_bounds__(256) void quant_transpose_i8(const float* __restrict__ x,
                                                          char* __restrict__ Xq) {
  __shared__ __align__(16) char T8[58 * 272];   // [w 0..57][c], +16B row pad
  const int h = blockIdx.x;                     // 0..55 -> padded row h+1
  const int b = blockIdx.y;
  const int tid = threadIdx.x;
  const int c = tid;

  // side borders w=0 and w=57
  T8[0 * 272 + c] = 0;
  T8[57 * 272 + c] = 0;

  const float4* src = (const float4*)(x + (((size_t)b * C_ + c) * H_ + h) * W_);
#pragma unroll
  for (int i = 0; i < 14; ++i) {
    float4 v = src[i];
    float vals[4] = {v.x, v.y, v.z, v.w};
    const int w0 = i * 4;
#pragma unroll
    for (int j = 0; j < 4; ++j) {
      int n = (int)rintf(vals[j] * QSCALE);
      n = n < 0 ? 0 : (n > 255 ? 255 : n);     // x<1 keeps n<=32; clamp for safety
      T8[(w0 + j + 1) * 272 + c] = (char)n;
    }
  }
  __syncthreads();

  char* Xb = Xq + (size_t)b * BSTR;
  // copy row h+1 of all 16 cig planes: 928 16B slots
#pragma unroll
  for (int p = 0; p < 4; ++p) {
    if (tid < 232) {
      const int w = tid % 58;
      const int cig = p * 4 + tid / 58;
      *(int4*)(Xb + (size_t)cig * PLANE + (h + 1) * 928 + w * 16) =
          *(const int4*)&T8[w * 272 + cig * 16];
    }
  }

  // top/bottom border rows
  if (h == 0 || h == 55) {
    const int hb = (h == 0) ? 0 : 57;
    const int4 z = {0, 0, 0, 0};
    for (int i = tid; i < 928; i += 256) {
      const int w = i % 58;
      const int cig = i / 58;
      *(int4*)(Xb + (size_t)cig * PLANE + hb * 928 + w * 16) = z;
    }
  }
}

// ---------------- Kernel 2: fused absmax + i8 error-feedback quant, one block per c_out ----
// Wt layout (linear): Wt[(step*256 + co)*64 + (ci & 63)], step = (ci>>6)*9 + pos.
__global__ __launch_bounds__(256) void prep_weights_i8(const float* __restrict__ w,
                                                       char* __restrict__ Wt,
                                                       float* __restrict__ oscale) {
  __shared__ __align__(16) float wf[2304];
  __shared__ __align__(16) char Wq[2304];       // [chunk=cc*9+p][ci&63]
  __shared__ float red[4];
  __shared__ float sbc;
  const int co = blockIdx.x;
  const int tid = threadIdx.x;

  const float4* src = (const float4*)(w + (size_t)co * 2304);
  float m = 0.f;
  for (int i = tid; i < 576; i += 256) {
    float4 v = src[i];
    *(float4*)&wf[i * 4] = v;
    m = fmaxf(fmaxf(fabsf(v.x), fabsf(v.y)), fmaxf(fmaxf(fabsf(v.z), fabsf(v.w)), m));
  }

#pragma unroll
  for (int off = 32; off; off >>= 1) m = fmaxf(m, __shfl_down(m, off));
  if ((tid & 63) == 0) red[tid >> 6] = m;
  __syncthreads();
  if (tid == 0) {
    m = fmaxf(fmaxf(red[0], red[1]), fmaxf(red[2], red[3]));
    m = fmaxf(m, 1e-20f);
    sbc = m;
    oscale[co] = (m / 127.f) * D1;
  }
  __syncthreads();

  if (tid < 9) {
    const int p = tid;
    const float s = sbc / 127.f;
    const float inv = 1.f / s;
    float carry = 0.f;
    for (int ci = 0; ci < 256; ++ci) {
      float t = wf[ci * 9 + p] + carry;
      float qf = rintf(t * inv);
      qf = fminf(fmaxf(qf, -128.f), 127.f);
      carry = t - qf * s;
      Wq[((ci >> 6) * 9 + p) * 64 + (ci & 63)] = (char)(int)qf;
    }
  }
  __syncthreads();

  if (tid < 144) {
    const int chunk = tid >> 2;        // step = cc*9 + p
    const int g = tid & 3;             // 16B group
    int4 v = *(const int4*)&Wq[chunk * 64 + (g << 4)];
    *(int4*)(Wt + ((size_t)(chunk * 256 + co)) * 64 + (g << 4)) = v;
  }
}

// ---------------- Kernel 3: implicit-GEMM conv, i8 MFMA 16x16x64 ---------------------------
// 4 waves, 128-reg cap (4 waves/SIMD). BM=128 co (2 m-frags/wave), BN=112 (2 rows, 7 n-frags).
// Grid 1792 = 2 co-halves x 28 by x 32 b. W: global->named-reg depth-2.
// X: ci-group-major LDS (linear global_load_lds staging, base+immediate ds_reads).
__global__ __launch_bounds__(256, 4) void conv_mfma_i8(const char* __restrict__ Xq,
                                                       const char* __restrict__ Wt,
                                                       const float* __restrict__ oscale,
                                                       float* __restrict__ out) {
  __shared__ __align__(16) char Xl[2][XBUFB];   // 29,696 B
  const int tid = threadIdx.x;
  const int wid = tid >> 6, lane = tid & 63;
  const int col = lane & 15, hi = lane >> 4;

  // XCD-aware bijective swizzle: 1792 = 8 XCDs x 224; co-half pairs stay adjacent
  const int l = blockIdx.x;
  const int wk = (l & 7) * 224 + (l >> 3);
  const int mh = wk & 1;
  const int rest = wk >> 1;          // 0..895
  const int by = rest % 28;
  const int b = rest / 28;
  const int h0 = 2 * by;

  int banf[7];
#pragma unroll
  for (int nf = 0; nf < 7; ++nf) {
    const int n_out = nf * 16 + col;
    const int r = n_out >= 56 ? 1 : 0;
    banf[nf] = hi * XROWB + (r * 58 + (n_out - r * 56)) * 16;
  }

  int32x4 acc[2][7];
#pragma unroll
  for (int mf = 0; mf < 2; ++mf)
#pragma unroll
    for (int nf = 0; nf < 7; ++nf) acc[mf][nf] = (int32x4){0, 0, 0, 0};

  const char* Xqb = Xq + (size_t)b * BSTR + h0 * 928;
  const char* wg = Wt + (size_t)((mh * 128 + wid * 32 + col) * 64 + hi * 16);

  int32x4 Wc0, Wc1, Wn0, Wn1;

  // ---- prologue: stage chunk 0 (cig 0..3), load W steps 0,1 ----
#pragma unroll
  for (int q = 0; q < 4; ++q)
    if (tid < 232) gload_lds16(Xqb + (size_t)q * PLANE + tid * 16,
                               (char*)Xl + q * XROWB + tid * 16);
  Wc0 = *(const int32x4*)(wg);
  Wc1 = *(const int32x4*)(wg + 1024);
  Wn0 = *(const int32x4*)(wg + 16384);
  Wn1 = *(const int32x4*)(wg + 16384 + 1024);
  __syncthreads();

#define MSTEP(POS, PROW16)                                                               \
  {                                                                                      \
    __builtin_amdgcn_s_setprio(1);                                                       \
    _Pragma("unroll") for (int nf = 0; nf < 7; ++nf) {                                   \
      int32x4 bb = *(const int32x4*)(xl + banf[nf] + (PROW16));                          \
      acc[0][nf] = __builtin_amdgcn_mfma_i32_16x16x64_i8(Wc0, bb, acc[0][nf], 0, 0, 0);  \
      acc[1][nf] = __builtin_amdgcn_mfma_i32_16x16x64_i8(Wc1, bb, acc[1][nf], 0, 0, 0);  \
    }                                                                                    \
    __builtin_amdgcn_s_setprio(0);                                                       \
    Wc0 = Wn0; Wc1 = Wn1;                                                                \
    Wn0 = *(const int32x4*)(wgcc + ((POS) + 2) * 16384);                                 \
    Wn1 = *(const int32x4*)(wgcc + ((POS) + 2) * 16384 + 1024);                          \
  }

  const char* wgcc = wg;
#pragma unroll 1
  for (int cc = 0; cc < 4; ++cc) {
    const bool st = (cc < 3);
    const char* xl = (const char*)Xl + (cc & 1) * XBUFB;
    char* xnxt = (char*)Xl + ((cc & 1) ^ 1) * XBUFB;
    const char* xsrc = Xqb + (size_t)(4 * (cc + 1)) * PLANE;

    if (st && tid < 232) gload_lds16(xsrc + tid * 16, xnxt + tid * 16);
    MSTEP(0, 0)
    if (st && tid < 232) gload_lds16(xsrc + (size_t)PLANE + tid * 16, xnxt + XROWB + tid * 16);
    MSTEP(1, 16)
    if (st && tid < 232) gload_lds16(xsrc + 2 * (size_t)PLANE + tid * 16,
                                     xnxt + 2 * XROWB + tid * 16);
    MSTEP(2, 32)
    if (st && tid < 232) gload_lds16(xsrc + 3 * (size_t)PLANE + tid * 16,
                                     xnxt + 3 * XROWB + tid * 16);
    MSTEP(3, 928)
    MSTEP(4, 944)
    MSTEP(5, 960)
    MSTEP(6, 1856)
    MSTEP(7, 1872)
    MSTEP(8, 1888)
    if (st) __syncthreads();
    wgcc += 9 * 16384;
  }
#undef MSTEP

  // ---- epilogue: out = acc * oscale[co]; C row = co (hi*4 + r4), col = spatial ----
#pragma unroll
  for (int mf = 0; mf < 2; ++mf) {
    const int cbase = mh * 128 + wid * 32 + mf * 16 + hi * 4;
    const float4 os = *(const float4*)(oscale + cbase);
#pragma unroll
    for (int nf = 0; nf < 7; ++nf) {
      const int n_out = nf * 16 + col;
      const int r = n_out >= 56 ? 1 : 0;
      const int hrow = h0 + r;
      const int wcol = n_out - r * 56;
      float* o = out + ((((size_t)b * 256 + cbase) * 56 + hrow) * 56 + wcol);
      o[0 * 3136] = (float)acc[mf][nf][0] * os.x;
      o[1 * 3136] = (float)acc[mf][nf][1] * os.y;
      o[2 * 3136] = (float)acc[mf][nf][2] * os.z;
      o[3 * 3136] = (float)acc[mf][nf][3] * os.w;
    }
  }
}

// ---------------- Fallback: naive direct conv (if ws too small) ----------------------------
__global__ void conv_naive(const float* __restrict__ x, const float* __restrict__ w,
                           float* __restrict__ out, int total) {
  int idx = blockIdx.x * 256 + threadIdx.x;
  if (idx >= total) return;
  const int wc = idx % 56;
  int t = idx / 56;
  const int hr = t % 56; t /= 56;
  const int co = t % 256;
  const int b = t / 256;
  float acc = 0.f;
  for (int ci = 0; ci < 256; ++ci) {
    const float* xb = x + (((size_t)b * 256 + ci) * 56) * 56;
    const float* wb = w + ((size_t)co * 256 + ci) * 9;
#pragma unroll
    for (int kh = 0; kh < 3; ++kh) {
      const int hh = hr + kh - 1;
      if (hh < 0 || hh >= 56) continue;
#pragma unroll
      for (int kw = 0; kw < 3; ++kw) {
        const int ww = wc + kw - 1;
        if (ww < 0 || ww >= 56) continue;
        const float q = rintf(xb[hh * 56 + ww] * QSCALE) * D1;
        acc += q * wb[kh * 3 + kw];
      }
    }
  }
  out[idx] = acc;
}

extern "C" void kernel_launch(void* const* d_in, const int* in_sizes, int n_in,
                              void* d_out, int out_size, void* d_ws, size_t ws_size,
                              hipStream_t stream) {
  (void)in_sizes; (void)n_in; (void)out_size;
  const float* x = (const float*)d_in[0];
  const float* w = (const float*)d_in[1];
  float* out = (float*)d_out;

  if (ws_size < WS_NEED) {
    const int total = B_ * C_ * H_ * W_;
    conv_naive<<<(total + 255) / 256, 256, 0, stream>>>(x, w, out, total);
    return;
  }

  char* Xq = (char*)d_ws;
  char* Wt = (char*)d_ws + XQ_SPACE;
  float* oscale = (float*)((char*)d_ws + XQ_SPACE + WT_SPACE);

  quant_transpose_i8<<<dim3(56, 32), 256, 0, stream>>>(x, Xq);
  prep_weights_i8<<<dim3(256), 256, 0, stream>>>(w, Wt, oscale);
  conv_mfma_i8<<<dim3(1792), 256, 0, stream>>>(Xq, Wt, oscale, out);
}